// Round 2
// baseline (386.443 us; speedup 1.0000x reference)
//
#include <hip/hip_runtime.h>
#include <hip/hip_bf16.h>

// Problem constants (match reference)
#define NN 100000
#define EE 1000000
#define FDIM 64
#define NREL 16
#define NBASE 8
#define HN (NN * FDIM)
#define H4 (HN / 4)
#define NB_SCAN ((NN + 255) / 256) // 391 scan blocks

typedef __attribute__((ext_vector_type(8))) short short8;
typedef __attribute__((ext_vector_type(4))) float f32x4;

static __device__ __forceinline__ ushort f2bf(float f) {
    __hip_bfloat16 b = __float2bfloat16(f);
    return *(ushort*)&b;
}
static __device__ __forceinline__ float bf2f(ushort u) {
    unsigned x = ((unsigned)u) << 16;
    float f;
    __builtin_memcpy(&f, &x, 4);
    return f;
}

// ---------------------------------------------------------------------------
// Algebra (verified against the harness-proven WT formula):
//   W[r][d][o] = sum_b w_comp[d&15][b] * V[4r+(d>>4)][b][o],
//   V[i'][b][o] = weight_flat[(i'*8+b)*64+o]
// With d = 16q+m:
//   h2[n][o] = sum_{u=4r+q, b} T[n][u][b] * weight_flat[(u*8+b)*64+o]
//   T[n][32*rel + j] += G[src][j]   (per edge, j in [0,32))
//   G[s][q*8+b] = sum_m h[s][16q+m] * w_comp[m][b]
// So the GEMM B-matrix is the RAW weight array viewed as [512][64].
// ---------------------------------------------------------------------------

// prep2: zero cnt; split-bf16 weight transpose WbT{h,l}[o][k=512]; G fp32 [N][32];
// relu h -> out.
__global__ __launch_bounds__(256) void prep2_kernel(
    const float4* __restrict__ h4, float4* __restrict__ out4,
    const float* __restrict__ h, const float* __restrict__ weight,
    const float* __restrict__ w_comp, float* __restrict__ G,
    ushort* __restrict__ WbTh, ushort* __restrict__ WbTl,
    int* __restrict__ cnt) {
    __shared__ float wc[128];
    if (threadIdx.x < 128) wc[threadIdx.x] = w_comp[threadIdx.x];
    __syncthreads();
    int gid = blockIdx.x * 256 + threadIdx.x;
    if (gid < NN) cnt[gid] = 0;
    if (gid < 32768) {                       // WbT[o][k] = weight_flat[k*64+o], hi/lo split
        int o = gid >> 9, k = gid & 511;
        float w = weight[k * 64 + o];
        ushort hi = f2bf(w);
        WbTh[gid] = hi;
        WbTl[gid] = f2bf(w - bf2f(hi));
    }
    if (gid < NN * 4) {                      // G[n][q*8+b]
        int n = gid >> 2, q = gid & 3;
        const float4* hp = (const float4*)(h + (size_t)n * 64 + q * 16);
        float hv[16];
#pragma unroll
        for (int m4 = 0; m4 < 4; ++m4) {
            float4 v = hp[m4];
            hv[4 * m4 + 0] = v.x; hv[4 * m4 + 1] = v.y;
            hv[4 * m4 + 2] = v.z; hv[4 * m4 + 3] = v.w;
        }
        float accb[8];
#pragma unroll
        for (int b = 0; b < 8; ++b) accb[b] = 0.f;
#pragma unroll
        for (int m = 0; m < 16; ++m) {
            float hm = hv[m];
#pragma unroll
            for (int b = 0; b < 8; ++b)
                accb[b] = fmaf(hm, wc[m * 8 + b], accb[b]);
        }
        float4* gp = (float4*)(G + (size_t)gid * 8);
        gp[0] = make_float4(accb[0], accb[1], accb[2], accb[3]);
        gp[1] = make_float4(accb[4], accb[5], accb[6], accb[7]);
    }
    if (gid < H4) {                          // relu output
        float4 v = h4[gid];
        v.x = fmaxf(v.x, 0.f); v.y = fmaxf(v.y, 0.f);
        v.z = fmaxf(v.z, 0.f); v.w = fmaxf(v.w, 0.f);
        out4[gid] = v;
    }
}

// dst histogram (after cnt zeroed in prep2)
__global__ __launch_bounds__(256) void histn_kernel(const int* __restrict__ dst,
                                                    int* __restrict__ cnt) {
    int stride = gridDim.x * 256;
    for (int i = blockIdx.x * 256 + threadIdx.x; i < EE; i += stride)
        atomicAdd(&cnt[dst[i]], 1);
}

// ---- multi-block exclusive scan of the 100k dst-histogram (3 tiny stages) ----
__global__ __launch_bounds__(256) void scan_a_kernel(const int* __restrict__ cnt,
                                                     int* __restrict__ bsum) {
    int i = blockIdx.x * 256 + threadIdx.x;
    int v = (i < NN) ? cnt[i] : 0;
#pragma unroll
    for (int o = 32; o > 0; o >>= 1) v += __shfl_down(v, o, 64);
    __shared__ int ws4[4];
    if ((threadIdx.x & 63) == 0) ws4[threadIdx.x >> 6] = v;
    __syncthreads();
    if (threadIdx.x == 0) bsum[blockIdx.x] = ws4[0] + ws4[1] + ws4[2] + ws4[3];
}

__global__ __launch_bounds__(512) void scan_b_kernel(const int* __restrict__ bsum,
                                                     int* __restrict__ bbase,
                                                     int* __restrict__ off) {
    __shared__ int lds[512];
    int t = threadIdx.x;
    int v = (t < NB_SCAN) ? bsum[t] : 0;
    lds[t] = v;
    __syncthreads();
    for (int o = 1; o < 512; o <<= 1) {
        int u = (t >= o) ? lds[t - o] : 0;
        __syncthreads();
        lds[t] += u;
        __syncthreads();
    }
    if (t < NB_SCAN) bbase[t] = lds[t] - v;
    if (t == NB_SCAN - 1) off[NN] = lds[t];
}

__global__ __launch_bounds__(256) void scan_c_kernel(const int* __restrict__ cnt,
                                                     const int* __restrict__ bbase,
                                                     int* __restrict__ off,
                                                     int* __restrict__ cur) {
    __shared__ int lds[256];
    int i = blockIdx.x * 256 + threadIdx.x;
    int t = threadIdx.x;
    int v = (i < NN) ? cnt[i] : 0;
    lds[t] = v;
    __syncthreads();
    for (int o = 1; o < 256; o <<= 1) {
        int u = (t >= o) ? lds[t - o] : 0;
        __syncthreads();
        lds[t] += u;
        __syncthreads();
    }
    if (i < NN) {
        int excl = lds[t] - v + bbase[blockIdx.x];
        off[i] = excl;
        cur[i] = excl;
    }
}

// Bucket edges by dst; payload pidx = src*16+rel.
__global__ void scatter_dst_kernel(const int* __restrict__ src, const int* __restrict__ dst,
                                   const int* __restrict__ rel, int* __restrict__ cur,
                                   int* __restrict__ pidx) {
    int i = blockIdx.x * blockDim.x + threadIdx.x;
    if (i < EE) {
        int pos = atomicAdd(&cur[dst[i]], 1);
        pidx[pos] = src[i] * 16 + rel[i];
    }
}

// Fused aggregate (edges -> T fp32 in LDS) + projection ([16x512]@[512x64] MFMA,
// split-bf16 hi/lo for ~fp32 accuracy). 16 dst nodes per block, 4 waves.
// LDS T row stride 516 f32 (pad) -> even bank spread for ds_read_b128.
__global__ __launch_bounds__(256) void agg_proj_kernel(
    const int* __restrict__ off, const int* __restrict__ pidx,
    const float* __restrict__ G, const ushort* __restrict__ WbTh,
    const ushort* __restrict__ WbTl, float* __restrict__ h2) {
    __shared__ __align__(16) float T[16][516];
    int t = threadIdx.x;
    float* Tf = &T[0][0];
    for (int i = t; i < 16 * 516; i += 256) Tf[i] = 0.f;
    __syncthreads();

    const int node0 = blockIdx.x * 16;
    const int wv = t >> 6;
    {
        // Each 32-lane half-wave owns 2 nodes sequentially -> no LDS write races,
        // plain += suffices (lanes write distinct j, halves write distinct rows).
        const int half = (t >> 5) & 1;
        const int j = t & 31;
#pragma unroll
        for (int s = 0; s < 2; ++s) {
            const int nl = (wv << 2) + (half << 1) + s;
            int e0 = off[node0 + nl];
            int e1 = off[node0 + nl + 1];
            float* trow = &T[nl][0];
            for (int e = e0; e < e1; ++e) {
                int p = pidx[e];                       // uniform across half-wave
                float g = G[((size_t)(p >> 4) << 5) + j]; // 128B coalesced row
                trow[((p & 15) << 5) + j] += g;
            }
        }
    }
    __syncthreads();

    const int lane = t & 63;
    const int quad = lane >> 4, l15 = lane & 15;
    f32x4 acc0 = (f32x4){0.f, 0.f, 0.f, 0.f};
    f32x4 acc1 = acc0, acc2 = acc0;
    const short8* bh = (const short8*)(WbTh + (size_t)(wv * 16 + l15) * 512);
    const short8* bl = (const short8*)(WbTl + (size_t)(wv * 16 + l15) * 512);
#pragma unroll
    for (int kk = 0; kk < 16; ++kk) {
        const float* ap = &T[l15][kk * 32 + quad * 8];
        f32x4 a0 = *(const f32x4*)ap;       // ds_read_b128, conflict-free (stride 516)
        f32x4 a1 = *(const f32x4*)(ap + 4);
        float av[8] = {a0[0], a0[1], a0[2], a0[3], a1[0], a1[1], a1[2], a1[3]};
        short8 ah, al;
#pragma unroll
        for (int i = 0; i < 8; ++i) {
            ushort hi = f2bf(av[i]);
            ah[i] = (short)hi;
            al[i] = (short)f2bf(av[i] - bf2f(hi));
        }
        short8 bhv = bh[kk * 4 + quad];
        short8 blv = bl[kk * 4 + quad];
        acc0 = __builtin_amdgcn_mfma_f32_16x16x32_bf16(ah, bhv, acc0, 0, 0, 0);
        acc1 = __builtin_amdgcn_mfma_f32_16x16x32_bf16(ah, blv, acc1, 0, 0, 0);
        acc2 = __builtin_amdgcn_mfma_f32_16x16x32_bf16(al, bhv, acc2, 0, 0, 0);
    }
    // C/D layout: col = lane&15, row = quad*4 + reg (HW-verified mapping)
    float* hp = h2 + (size_t)(node0 + quad * 4) * 64 + wv * 16 + l15;
#pragma unroll
    for (int r = 0; r < 4; ++r)
        hp[(size_t)r * 64] = acc0[r] + acc1[r] + acc2[r];
}

extern "C" void kernel_launch(void* const* d_in, const int* in_sizes, int n_in,
                              void* d_out, int out_size, void* d_ws, size_t ws_size,
                              hipStream_t stream) {
    const float* h      = (const float*)d_in[0];
    const float* weight = (const float*)d_in[1];
    const float* w_comp = (const float*)d_in[2];
    const int*   src    = (const int*)d_in[3];
    const int*   dst    = (const int*)d_in[4];
    const int*   rel    = (const int*)d_in[5];

    float* out_hnew = (float*)d_out;
    float* out_h2   = out_hnew + HN;

    char* ws = (char*)d_ws;

    // Workspace layout (all offsets 16B-aligned); total ~18.1 MB
    ushort* WbTh  = (ushort*)ws;                    // 64 KB
    ushort* WbTl  = (ushort*)(ws + 65536);          // 64 KB
    int*    cnt   = (int*)(ws + 131072);            // 100000 ints
    int*    off   = (int*)(ws + 531072);            // 100001 ints (+pad)
    int*    cur   = (int*)(ws + 931088);            // 100000 ints
    int*    pidx  = (int*)(ws + 1331088);           // 1M ints
    int*    bsum  = (int*)(ws + 5331088);           // 392 ints
    int*    bbase = (int*)(ws + 5332656);           // 392 ints
    float*  G     = (float*)(ws + 5334224);         // N x 32 fp32 = 12.8 MB

    hipLaunchKernelGGL(prep2_kernel, dim3(H4 / 256), dim3(256), 0, stream,
                       (const float4*)h, (float4*)out_hnew, h, weight, w_comp,
                       G, WbTh, WbTl, cnt);
    hipLaunchKernelGGL(histn_kernel, dim3(1024), dim3(256), 0, stream, dst, cnt);
    hipLaunchKernelGGL(scan_a_kernel, dim3(NB_SCAN), dim3(256), 0, stream, cnt, bsum);
    hipLaunchKernelGGL(scan_b_kernel, dim3(1), dim3(512), 0, stream, bsum, bbase, off);
    hipLaunchKernelGGL(scan_c_kernel, dim3(NB_SCAN), dim3(256), 0, stream,
                       cnt, bbase, off, cur);
    hipLaunchKernelGGL(scatter_dst_kernel, dim3((EE + 255) / 256), dim3(256), 0, stream,
                       src, dst, rel, cur, pidx);
    hipLaunchKernelGGL(agg_proj_kernel, dim3(NN / 16), dim3(256), 0, stream,
                       off, pidx, G, WbTh, WbTl, out_h2);
}